// Round 9
// baseline (9737.107 us; speedup 1.0000x reference)
//
#include <hip/hip_runtime.h>
#include <hip/hip_bf16.h>
#include <stdint.h>

// Round 9: r8 architecture (wave-granular flags + bulk h load, measured best)
// with latency-chain compression: (1) pipelined 2-deep flag polling via counted
// vmcnt(1) -> observe granularity ~RTT/2; (2) per-mb early h publish (mb0's
// store issues before mb1's combine); (3) independent shfl_xor(v,3) instead of
// the dependent shuffle chain. Arithmetic bit-identical to rounds 3/8.

typedef __attribute__((ext_vector_type(8))) short bf16x8;
typedef __attribute__((ext_vector_type(4))) float f32x4;
typedef __attribute__((ext_vector_type(4))) int i32x4;

__device__ __forceinline__ unsigned short f2bf(float f) {
    union { float f; unsigned int u; } v; v.f = f;
    unsigned int u = v.u;
    return (unsigned short)((u + 0x7fffu + ((u >> 16) & 1u)) >> 16);  // RNE
}
__device__ __forceinline__ float bf2f(unsigned short b) {
    union { unsigned int u; float f; } v; v.u = ((unsigned int)b) << 16;
    return v.f;
}
__device__ __forceinline__ float fsig(float x) { return 1.f / (1.f + __expf(-x)); }
__device__ __forceinline__ float ftanh(float x) { return 1.f - 2.f / (1.f + __expf(2.f * x)); }

// ---- MALL-coherent access (bypass L1+L2 via sc0 sc1; proven rounds 3-8) ----

__device__ __forceinline__ void coh_ld32_issue(unsigned int& d, const void* p) {
    asm volatile("global_load_dword %0, %1, off sc0 sc1" : "=v"(d) : "v"(p) : "memory");
}
__device__ __forceinline__ void coh_ld128_issue(i32x4& d, const void* p) {
    asm volatile("global_load_dwordx4 %0, %1, off sc0 sc1" : "=&v"(d) : "v"(p) : "memory");
}
__device__ __forceinline__ void coh_st32(void* p, unsigned int v) {
    asm volatile("global_store_dword %0, %1, off sc0 sc1" :: "v"(p), "v"(v) : "memory");
}
__device__ __forceinline__ void vm_drain() {
    asm volatile("s_waitcnt vmcnt(0)" ::: "memory");
}
__device__ __forceinline__ void vm_wait1() {
    asm volatile("s_waitcnt vmcnt(1)" ::: "memory");
}

// ---------------- pack kernels (fp32 -> bf16, with K padding) ----------------

__global__ void pack_x_kernel(const float* __restrict__ x, unsigned short* __restrict__ xp,
                              int M, int K, int Kp) {
    int total = M * Kp;
    for (int idx = blockIdx.x * blockDim.x + threadIdx.x; idx < total;
         idx += gridDim.x * blockDim.x) {
        int r = idx / Kp, k = idx - r * Kp;
        xp[idx] = (k < K) ? f2bf(x[(size_t)r * K + k]) : (unsigned short)0;
    }
}

__global__ void pack_w_kernel(const float* __restrict__ Wf, const float* __restrict__ Wi,
                              const float* __restrict__ Wo, const float* __restrict__ Wc,
                              unsigned short* __restrict__ out, int K, int Kp) {
    int total = 2048 * Kp;
    for (int idx = blockIdx.x * blockDim.x + threadIdx.x; idx < total;
         idx += gridDim.x * blockDim.x) {
        int n = idx / Kp, k = idx - n * Kp;
        int gate = n >> 9, j = n & 511;
        const float* W = (gate == 0) ? Wf : (gate == 1) ? Wi : (gate == 2) ? Wo : Wc;
        out[idx] = (k < K) ? f2bf(W[(size_t)j * K + k]) : (unsigned short)0;
    }
}

// ---------------- gate GEMM (validated rounds 1-8) ----------------

__global__ __launch_bounds__(256) void gemm_gates(
    const unsigned short* __restrict__ A, const unsigned short* __restrict__ Bm,
    const float* __restrict__ bF, const float* __restrict__ bI,
    const float* __restrict__ bO, const float* __restrict__ bC,
    unsigned short* __restrict__ G, int Kp) {
    __shared__ unsigned short Alds[64][32];
    __shared__ unsigned short Blds[64][32];
    const int tid = threadIdx.x;
    const int m0 = blockIdx.x * 64;
    const int n0 = blockIdx.y * 64;
    const int w = tid >> 6, l = tid & 63;
    const int lr = l & 15, lk = (l >> 4) * 8;
    const int ldrow = tid >> 2;
    const int ldk = (tid & 3) * 8;
    const unsigned short* Aptr = A + (size_t)(m0 + ldrow) * Kp + ldk;
    const unsigned short* Bptr = Bm + (size_t)(n0 + ldrow) * Kp + ldk;

    f32x4 zero = {0.f, 0.f, 0.f, 0.f};
    f32x4 acc0 = zero, acc1 = zero, acc2 = zero, acc3 = zero;

    for (int k0 = 0; k0 < Kp; k0 += 32) {
        *(uint4*)&Alds[ldrow][ldk] = *(const uint4*)(Aptr + k0);
        *(uint4*)&Blds[ldrow][ldk] = *(const uint4*)(Bptr + k0);
        __syncthreads();
        bf16x8 a = *(const bf16x8*)&Alds[w * 16 + lr][lk];
        bf16x8 b0 = *(const bf16x8*)&Blds[0 * 16 + lr][lk];
        bf16x8 b1 = *(const bf16x8*)&Blds[1 * 16 + lr][lk];
        bf16x8 b2 = *(const bf16x8*)&Blds[2 * 16 + lr][lk];
        bf16x8 b3 = *(const bf16x8*)&Blds[3 * 16 + lr][lk];
        acc0 = __builtin_amdgcn_mfma_f32_16x16x32_bf16(a, b0, acc0, 0, 0, 0);
        acc1 = __builtin_amdgcn_mfma_f32_16x16x32_bf16(a, b1, acc1, 0, 0, 0);
        acc2 = __builtin_amdgcn_mfma_f32_16x16x32_bf16(a, b2, acc2, 0, 0, 0);
        acc3 = __builtin_amdgcn_mfma_f32_16x16x32_bf16(a, b3, acc3, 0, 0, 0);
        __syncthreads();
    }
    const int gate = n0 >> 9;
    const float* bias = (gate == 0) ? bF : (gate == 1) ? bI : (gate == 2) ? bO : bC;
    f32x4 accs[4] = {acc0, acc1, acc2, acc3};
#pragma unroll
    for (int c = 0; c < 4; ++c) {
        int col = n0 + c * 16 + lr;
        float bv = bias[col & 511];
#pragma unroll
        for (int r = 0; r < 4; ++r) {
            int row = m0 + w * 16 + (l >> 4) * 4 + r;
            G[(size_t)row * 2048 + col] = f2bf(accs[c][r] + bv);
        }
    }
}

// ---------------- recurrence: 32 wgs, wave-granular flags (r8) ---------------
// + pipelined poll, early publish, independent shuffles.

template <int LAYER>
__global__ __launch_bounds__(256, 1) void lstm_rec10(
    const unsigned short* __restrict__ U, const unsigned short* __restrict__ G,
    unsigned short* __restrict__ y_bf, float* __restrict__ y_f32,
    unsigned int* __restrict__ h_frag, unsigned int* __restrict__ flags, int T) {
    __shared__ unsigned short wlds[4 * 16 * 64 * 8];       // 64 KB weights
    __shared__ unsigned short hstage[2][16 * 64 * 8 * 2];  // 2 x 32 KB h (dbuf)

    const int tid = threadIdx.x;
    const int w = tid >> 6;
    const int l = tid & 63;
    const int wg = blockIdx.x;
    const int j0 = wg * 16;
    const int g = l & 3;
    const int q = (l & 15) >> 2;
    const int jl = 4 * w + q;
    const int m0 = (l >> 4) * 4 + g;
    const int mrow = (l >> 4) * 4;
    const int colg = g * 512 + j0 + jl;
    const int kcw = wg >> 1;
    const int jlq = ((wg & 1) << 4) + jl;
    const int lslot = m0 + 16 * (jlq >> 3);
    const int jb = jlq & 7;
    const int fid0 = (0 * 16 + kcw) * 256 + lslot * 4 + (jb >> 1);
    const int fid1 = (1 * 16 + kcw) * 256 + lslot * 4 + (jb >> 1);
    unsigned int* const flagp = flags + (size_t)(wg * 4 + w) * 32;
    const unsigned int* const pollp = flags + (size_t)(32 * w + (l & 31)) * 32;

    // stage weight fragments into LDS (frag-major, conflict-free reads)
    for (int e = tid; e < 4096; e += 256) {
        int fl = e >> 6;
        int ll = e & 63;
        int nt = fl >> 4, kc = fl & 15;
        int nl = nt * 16 + (ll & 15);
        int jj = nl >> 2, gg = nl & 3;
        int nglob = gg * 512 + j0 + jj;
        int k = kc * 32 + (ll >> 4) * 8;
        *(uint4*)&wlds[(size_t)e * 8] = *(const uint4*)&U[(size_t)nglob * 512 + k];
    }

    // G prefetch for step 0
    unsigned short gpf[2][4];
    {
        const unsigned short* gf_ = G + (size_t)mrow * 2048 + colg;
        const unsigned short* gb_ = G + (size_t)((T - 1) * 16 + mrow) * 2048 + colg;
#pragma unroll
        for (int r = 0; r < 4; ++r) {
            gpf[0][r] = gf_[r * 2048];
            gpf[1][r] = gb_[r * 2048];
        }
    }

    float cst[2][4] = {{0.f, 0.f, 0.f, 0.f}, {0.f, 0.f, 0.f, 0.f}};

    for (int s = 0; s < T; ++s) {
        if (s > 0) {
            // ---- pipelined 2-deep flag poll (observe granularity ~RTT/2) ----
            {
                const unsigned tgt = (unsigned)(s + 1);
                unsigned a = 0, b = 0;
                int guard = 0;
                coh_ld32_issue(a, pollp);
                for (;;) {
                    coh_ld32_issue(b, pollp);
                    vm_wait1();
                    __builtin_amdgcn_sched_barrier(0);
                    if (__all(a >= tgt)) break;
                    coh_ld32_issue(a, pollp);
                    vm_wait1();
                    __builtin_amdgcn_sched_barrier(0);
                    if (__all(b >= tgt)) break;
                    if (++guard > (1 << 13)) break;  // bounded: bug -> visible error
                }
            }
            // ---- stage this wave's 16 strips (8 KB) into hstage[s&1] ----
            {
                const unsigned int* src = h_frag + (size_t)(s & 1) * 8192;
                unsigned int* dst = (unsigned int*)hstage[s & 1];
                const int half = (l >> 5);  // 0: mb0 strips, 1: mb1 strips
                i32x4 v[8];
                int gd[8];
#pragma unroll
                for (int i = 0; i < 8; ++i) {
                    int strip = half * 32 + 8 * w + i;
                    gd[i] = strip * 128 + (l & 31) * 4;
                    coh_ld128_issue(v[i], src + gd[i]);
                }
                vm_drain();  // also absorbs the one leftover poll load
                __builtin_amdgcn_sched_barrier(0);  // rule 18
#pragma unroll
                for (int i = 0; i < 8; ++i) *(i32x4*)(dst + gd[i]) = v[i];
            }
        }
        __syncthreads();  // all waves staged hstage[s&1]; dbuf protects prev parity

        // ---- MFMA: (32 x 512) h x (512 x 16) U-tile ----
        f32x4 acc0 = {0.f, 0.f, 0.f, 0.f};
        f32x4 acc1 = {0.f, 0.f, 0.f, 0.f};
        if (s > 0) {
            const unsigned short* hs = hstage[s & 1];
#pragma unroll
            for (int kc = 0; kc < 16; ++kc) {
                bf16x8 a0 = *(const bf16x8*)&hs[((size_t)(0 * 16 + kc) * 64 + l) * 8];
                bf16x8 a1 = *(const bf16x8*)&hs[((size_t)(1 * 16 + kc) * 64 + l) * 8];
                bf16x8 bw = *(const bf16x8*)&wlds[(((size_t)w * 16 + kc) * 64 + l) * 8];
                acc0 = __builtin_amdgcn_mfma_f32_16x16x32_bf16(a0, bw, acc0, 0, 0, 0);
                acc1 = __builtin_amdgcn_mfma_f32_16x16x32_bf16(a1, bw, acc1, 0, 0, 0);
            }
        }

        // ---- combine + EARLY per-mb publish (mb0 store before mb1 combine) ----
        float hsel[2];
        unsigned hww[2];
        unsigned int* hfw = h_frag + (size_t)((s + 1) & 1) * 8192;
#pragma unroll
        for (int mb = 0; mb < 2; ++mb) {
            f32x4 acc = mb ? acc1 : acc0;
#pragma unroll
            for (int r = 0; r < 4; ++r) {
                float v = acc[r] + bf2f(gpf[mb][r]);
                float x1 = __shfl_xor(v, 1, 64);
                float x2 = __shfl_xor(v, 2, 64);
                float x3 = __shfl_xor(v, 3, 64);  // == shfl(shfl(v,1),2), independent
                bool b0 = (g & 1) != 0, b1 = (g & 2) != 0;
                float gf = b1 ? (b0 ? x3 : x2) : (b0 ? x1 : v);
                float gi = b1 ? (b0 ? x2 : x3) : (b0 ? v : x1);
                float go = b1 ? (b0 ? x1 : v) : (b0 ? x3 : x2);
                float gc = b1 ? (b0 ? v : x1) : (b0 ? x2 : x3);
                float ft = fsig(gf), it = fsig(gi), ot = fsig(go);
                float cn = it * ftanh(gc) + ft * cst[mb][r];
                cst[mb][r] = cn;
                float hn = ot * ftanh(cn);
                if (r == g) hsel[mb] = hn;
            }
            unsigned b16 = (unsigned)f2bf(hsel[mb]);
            unsigned ho = (unsigned)__shfl_xor((int)b16, 4, 64);
            hww[mb] = b16 | (ho << 16);
            if ((q & 1) == 0) coh_st32(hfw + (mb ? fid1 : fid0), hww[mb]);
        }

        // ---- per-wave drain (own h stores) -> per-wave flag ----
        vm_drain();
        if (l == 0) coh_st32(flagp, (unsigned)(s + 2));

        // ---- G prefetch for s+1 + y stores (ack during next poll window) ----
        float ho0 = __shfl_xor(hsel[0], 4, 64);
        float ho1 = __shfl_xor(hsel[1], 4, 64);
        {
            int sn = (s + 1 < T) ? (s + 1) : (T - 1);
            const unsigned short* gf_ = G + (size_t)(sn * 16 + mrow) * 2048 + colg;
            const unsigned short* gb_ = G + (size_t)((T - 1 - sn) * 16 + mrow) * 2048 + colg;
#pragma unroll
            for (int r = 0; r < 4; ++r) {
                gpf[0][r] = gf_[r * 2048];
                gpf[1][r] = gb_[r * 2048];
            }
        }
        if ((q & 1) == 0) {
#pragma unroll
            for (int mb = 0; mb < 2; ++mb) {
                int row = (mb ? (T - 1 - s) : s) * 16 + m0;
                int col = mb * 512 + j0 + jl;
                if (LAYER == 0) {
                    *(unsigned int*)&y_bf[(size_t)row * 1024 + col] = hww[mb];
                } else {
                    float2 fv = make_float2(hsel[mb], mb ? ho1 : ho0);
                    *(float2*)&y_f32[(size_t)row * 1024 + col] = fv;
                }
            }
        }
    }
}

// ---------------- host ----------------

extern "C" void kernel_launch(void* const* d_in, const int* in_sizes, int n_in,
                              void* d_out, int out_size, void* d_ws, size_t ws_size,
                              hipStream_t stream) {
    (void)in_sizes; (void)n_in; (void)out_size; (void)ws_size;
    const int T = 1000, M = T * 16;
    const int K0 = 440, K0p = 448, K1 = 1024;

    char* ws = (char*)d_ws;
    size_t off = 0;
    auto alloc = [&](size_t bytes) -> void* {
        void* p = ws + off;
        off += (bytes + 255) & ~(size_t)255;
        return p;
    };
    unsigned short* G  = (unsigned short*)alloc((size_t)M * 2048 * 2);
    unsigned short* xp = (unsigned short*)alloc((size_t)M * K0p * 2);
    unsigned short* W0 = (unsigned short*)alloc((size_t)2048 * K0p * 2);
    unsigned short* W1 = (unsigned short*)alloc((size_t)2048 * K1 * 2);
    unsigned short* U0 = (unsigned short*)alloc((size_t)2048 * 512 * 2);
    unsigned short* U1 = (unsigned short*)alloc((size_t)2048 * 512 * 2);
    unsigned short* y0 = (unsigned short*)alloc((size_t)M * 1024 * 2);
    unsigned int* hf0  = (unsigned int*)alloc((size_t)2 * 8192 * 4);
    unsigned int* hf1  = (unsigned int*)alloc((size_t)2 * 8192 * 4);
    unsigned int* fl0  = (unsigned int*)alloc((size_t)128 * 32 * 4);
    unsigned int* fl1  = (unsigned int*)alloc((size_t)128 * 32 * 4);

    const float* x = (const float*)d_in[0];

    hipMemsetAsync(fl0, 0, 128 * 32 * 4, stream);
    hipMemsetAsync(fl1, 0, 128 * 32 * 4, stream);

    pack_x_kernel<<<2048, 256, 0, stream>>>(x, xp, M, K0, K0p);
    pack_w_kernel<<<1024, 256, 0, stream>>>((const float*)d_in[1], (const float*)d_in[4],
                                            (const float*)d_in[7], (const float*)d_in[10],
                                            W0, K0, K0p);
    pack_w_kernel<<<1024, 256, 0, stream>>>((const float*)d_in[3], (const float*)d_in[6],
                                            (const float*)d_in[9], (const float*)d_in[12],
                                            U0, 512, 512);
    pack_w_kernel<<<1024, 256, 0, stream>>>((const float*)d_in[13], (const float*)d_in[16],
                                            (const float*)d_in[19], (const float*)d_in[22],
                                            W1, K1, K1);
    pack_w_kernel<<<1024, 256, 0, stream>>>((const float*)d_in[15], (const float*)d_in[18],
                                            (const float*)d_in[21], (const float*)d_in[24],
                                            U1, 512, 512);

    dim3 blk(256);
    dim3 g0(M / 64, 2048 / 64);
    gemm_gates<<<g0, blk, 0, stream>>>(xp, W0, (const float*)d_in[2], (const float*)d_in[5],
                                       (const float*)d_in[8], (const float*)d_in[11], G, K0p);
    lstm_rec10<0><<<32, 256, 0, stream>>>(U0, G, y0, nullptr, hf0, fl0, T);
    gemm_gates<<<g0, blk, 0, stream>>>(y0, W1, (const float*)d_in[14], (const float*)d_in[17],
                                       (const float*)d_in[20], (const float*)d_in[23], G, K1);
    lstm_rec10<1><<<32, 256, 0, stream>>>(U1, G, nullptr, (float*)d_out, hf1, fl1, T);
}

// Round 10
// 8836.144 us; speedup vs baseline: 1.1020x; 1.1020x over previous
//
#include <hip/hip_runtime.h>
#include <hip/hip_bf16.h>
#include <stdint.h>

// Round 10: r8 architecture exactly (single-deep poll, wave-granular flags,
// bulk h staging, dbuf hstage) with three TRAFFIC-NEUTRAL issue-order fixes:
// (1) G prefetch double-buffered, issued right after staging barrier (off the
//     next poll's vmcnt(0) path, hidden under MFMA+combine);
// (2) y stores issued with the h stores so the pre-flag drain absorbs their
//     acks in parallel (next poll no longer inherits them);
// (3) independent shfl_xor(v,3) + per-mb early h publish.
// r9's 2-deep poll REVERTED (doubled poll traffic -> contention regression).
// Arithmetic bit-identical to validated rounds 3/8/9.

typedef __attribute__((ext_vector_type(8))) short bf16x8;
typedef __attribute__((ext_vector_type(4))) float f32x4;
typedef __attribute__((ext_vector_type(4))) int i32x4;

__device__ __forceinline__ unsigned short f2bf(float f) {
    union { float f; unsigned int u; } v; v.f = f;
    unsigned int u = v.u;
    return (unsigned short)((u + 0x7fffu + ((u >> 16) & 1u)) >> 16);  // RNE
}
__device__ __forceinline__ float bf2f(unsigned short b) {
    union { unsigned int u; float f; } v; v.u = ((unsigned int)b) << 16;
    return v.f;
}
__device__ __forceinline__ float fsig(float x) { return 1.f / (1.f + __expf(-x)); }
__device__ __forceinline__ float ftanh(float x) { return 1.f - 2.f / (1.f + __expf(2.f * x)); }

// ---- MALL-coherent access (bypass L1+L2 via sc0 sc1; proven rounds 3-9) ----

__device__ __forceinline__ unsigned int coh_ld32(const void* p) {
    unsigned int v;
    asm volatile("global_load_dword %0, %1, off sc0 sc1\n\ts_waitcnt vmcnt(0)"
                 : "=v"(v) : "v"(p) : "memory");
    return v;
}
__device__ __forceinline__ void coh_ld128_issue(i32x4& d, const void* p) {
    asm volatile("global_load_dwordx4 %0, %1, off sc0 sc1" : "=&v"(d) : "v"(p) : "memory");
}
__device__ __forceinline__ void coh_st32(void* p, unsigned int v) {
    asm volatile("global_store_dword %0, %1, off sc0 sc1" :: "v"(p), "v"(v) : "memory");
}
__device__ __forceinline__ void vm_drain() {
    asm volatile("s_waitcnt vmcnt(0)" ::: "memory");
}

// ---------------- pack kernels (fp32 -> bf16, with K padding) ----------------

__global__ void pack_x_kernel(const float* __restrict__ x, unsigned short* __restrict__ xp,
                              int M, int K, int Kp) {
    int total = M * Kp;
    for (int idx = blockIdx.x * blockDim.x + threadIdx.x; idx < total;
         idx += gridDim.x * blockDim.x) {
        int r = idx / Kp, k = idx - r * Kp;
        xp[idx] = (k < K) ? f2bf(x[(size_t)r * K + k]) : (unsigned short)0;
    }
}

__global__ void pack_w_kernel(const float* __restrict__ Wf, const float* __restrict__ Wi,
                              const float* __restrict__ Wo, const float* __restrict__ Wc,
                              unsigned short* __restrict__ out, int K, int Kp) {
    int total = 2048 * Kp;
    for (int idx = blockIdx.x * blockDim.x + threadIdx.x; idx < total;
         idx += gridDim.x * blockDim.x) {
        int n = idx / Kp, k = idx - n * Kp;
        int gate = n >> 9, j = n & 511;
        const float* W = (gate == 0) ? Wf : (gate == 1) ? Wi : (gate == 2) ? Wo : Wc;
        out[idx] = (k < K) ? f2bf(W[(size_t)j * K + k]) : (unsigned short)0;
    }
}

// ---------------- gate GEMM (validated rounds 1-9) ----------------

__global__ __launch_bounds__(256) void gemm_gates(
    const unsigned short* __restrict__ A, const unsigned short* __restrict__ Bm,
    const float* __restrict__ bF, const float* __restrict__ bI,
    const float* __restrict__ bO, const float* __restrict__ bC,
    unsigned short* __restrict__ G, int Kp) {
    __shared__ unsigned short Alds[64][32];
    __shared__ unsigned short Blds[64][32];
    const int tid = threadIdx.x;
    const int m0 = blockIdx.x * 64;
    const int n0 = blockIdx.y * 64;
    const int w = tid >> 6, l = tid & 63;
    const int lr = l & 15, lk = (l >> 4) * 8;
    const int ldrow = tid >> 2;
    const int ldk = (tid & 3) * 8;
    const unsigned short* Aptr = A + (size_t)(m0 + ldrow) * Kp + ldk;
    const unsigned short* Bptr = Bm + (size_t)(n0 + ldrow) * Kp + ldk;

    f32x4 zero = {0.f, 0.f, 0.f, 0.f};
    f32x4 acc0 = zero, acc1 = zero, acc2 = zero, acc3 = zero;

    for (int k0 = 0; k0 < Kp; k0 += 32) {
        *(uint4*)&Alds[ldrow][ldk] = *(const uint4*)(Aptr + k0);
        *(uint4*)&Blds[ldrow][ldk] = *(const uint4*)(Bptr + k0);
        __syncthreads();
        bf16x8 a = *(const bf16x8*)&Alds[w * 16 + lr][lk];
        bf16x8 b0 = *(const bf16x8*)&Blds[0 * 16 + lr][lk];
        bf16x8 b1 = *(const bf16x8*)&Blds[1 * 16 + lr][lk];
        bf16x8 b2 = *(const bf16x8*)&Blds[2 * 16 + lr][lk];
        bf16x8 b3 = *(const bf16x8*)&Blds[3 * 16 + lr][lk];
        acc0 = __builtin_amdgcn_mfma_f32_16x16x32_bf16(a, b0, acc0, 0, 0, 0);
        acc1 = __builtin_amdgcn_mfma_f32_16x16x32_bf16(a, b1, acc1, 0, 0, 0);
        acc2 = __builtin_amdgcn_mfma_f32_16x16x32_bf16(a, b2, acc2, 0, 0, 0);
        acc3 = __builtin_amdgcn_mfma_f32_16x16x32_bf16(a, b3, acc3, 0, 0, 0);
        __syncthreads();
    }
    const int gate = n0 >> 9;
    const float* bias = (gate == 0) ? bF : (gate == 1) ? bI : (gate == 2) ? bO : bC;
    f32x4 accs[4] = {acc0, acc1, acc2, acc3};
#pragma unroll
    for (int c = 0; c < 4; ++c) {
        int col = n0 + c * 16 + lr;
        float bv = bias[col & 511];
#pragma unroll
        for (int r = 0; r < 4; ++r) {
            int row = m0 + w * 16 + (l >> 4) * 4 + r;
            G[(size_t)row * 2048 + col] = f2bf(accs[c][r] + bv);
        }
    }
}

// ---------------- recurrence: 32 wgs, wave-granular flags (r8 + fixes) --------

template <int LAYER>
__global__ __launch_bounds__(256, 1) void lstm_rec11(
    const unsigned short* __restrict__ U, const unsigned short* __restrict__ G,
    unsigned short* __restrict__ y_bf, float* __restrict__ y_f32,
    unsigned int* __restrict__ h_frag, unsigned int* __restrict__ flags, int T) {
    __shared__ unsigned short wlds[4 * 16 * 64 * 8];       // 64 KB weights
    __shared__ unsigned short hstage[2][16 * 64 * 8 * 2];  // 2 x 32 KB h (dbuf)

    const int tid = threadIdx.x;
    const int w = tid >> 6;
    const int l = tid & 63;
    const int wg = blockIdx.x;
    const int j0 = wg * 16;
    const int g = l & 3;
    const int q = (l & 15) >> 2;
    const int jl = 4 * w + q;
    const int m0 = (l >> 4) * 4 + g;
    const int mrow = (l >> 4) * 4;
    const int colg = g * 512 + j0 + jl;
    const int kcw = wg >> 1;
    const int jlq = ((wg & 1) << 4) + jl;
    const int lslot = m0 + 16 * (jlq >> 3);
    const int jb = jlq & 7;
    const int fid0 = (0 * 16 + kcw) * 256 + lslot * 4 + (jb >> 1);
    const int fid1 = (1 * 16 + kcw) * 256 + lslot * 4 + (jb >> 1);
    unsigned int* const flagp = flags + (size_t)(wg * 4 + w) * 32;
    const unsigned int* const pollp = flags + (size_t)(32 * w + (l & 31)) * 32;

    // stage weight fragments into LDS (frag-major, conflict-free reads)
    for (int e = tid; e < 4096; e += 256) {
        int fl = e >> 6;
        int ll = e & 63;
        int nt = fl >> 4, kc = fl & 15;
        int nl = nt * 16 + (ll & 15);
        int jj = nl >> 2, gg = nl & 3;
        int nglob = gg * 512 + j0 + jj;
        int k = kc * 32 + (ll >> 4) * 8;
        *(uint4*)&wlds[(size_t)e * 8] = *(const uint4*)&U[(size_t)nglob * 512 + k];
    }

    // G prefetch for step 0
    unsigned short gpf[2][4];
    {
        const unsigned short* gf_ = G + (size_t)mrow * 2048 + colg;
        const unsigned short* gb_ = G + (size_t)((T - 1) * 16 + mrow) * 2048 + colg;
#pragma unroll
        for (int r = 0; r < 4; ++r) {
            gpf[0][r] = gf_[r * 2048];
            gpf[1][r] = gb_[r * 2048];
        }
    }

    float cst[2][4] = {{0.f, 0.f, 0.f, 0.f}, {0.f, 0.f, 0.f, 0.f}};

    for (int s = 0; s < T; ++s) {
        if (s > 0) {
            // ---- single-deep wave-parallel poll (r8 form; 2-deep regressed) ----
            {
                const unsigned tgt = (unsigned)(s + 1);
                int guard = 0;
                for (;;) {
                    unsigned u = 0xFFFFFFFFu;
                    if (l < 32) u = coh_ld32(pollp);
                    if (__all(u >= tgt) || ++guard > (1 << 14)) break;
                }
            }
            // ---- stage this wave's 16 strips (8 KB) into hstage[s&1] ----
            {
                const unsigned int* src = h_frag + (size_t)(s & 1) * 8192;
                unsigned int* dst = (unsigned int*)hstage[s & 1];
                const int half = (l >> 5);  // 0: mb0 strips, 1: mb1 strips
                i32x4 v[8];
                int gd[8];
#pragma unroll
                for (int i = 0; i < 8; ++i) {
                    int strip = half * 32 + 8 * w + i;
                    gd[i] = strip * 128 + (l & 31) * 4;
                    coh_ld128_issue(v[i], src + gd[i]);
                }
                vm_drain();
                __builtin_amdgcn_sched_barrier(0);  // rule 18
#pragma unroll
                for (int i = 0; i < 8; ++i) *(i32x4*)(dst + gd[i]) = v[i];
            }
        }
        __syncthreads();  // all waves staged hstage[s&1]; dbuf protects prev parity

        // ---- consume G into gcur; prefetch s+1 NOW (hides under MFMA+combine,
        //      off the next poll's vmcnt(0) path) ----
        unsigned short gcur[2][4];
#pragma unroll
        for (int r = 0; r < 4; ++r) {
            gcur[0][r] = gpf[0][r];
            gcur[1][r] = gpf[1][r];
        }
        {
            int sn = (s + 1 < T) ? (s + 1) : (T - 1);
            const unsigned short* gf_ = G + (size_t)(sn * 16 + mrow) * 2048 + colg;
            const unsigned short* gb_ = G + (size_t)((T - 1 - sn) * 16 + mrow) * 2048 + colg;
#pragma unroll
            for (int r = 0; r < 4; ++r) {
                gpf[0][r] = gf_[r * 2048];
                gpf[1][r] = gb_[r * 2048];
            }
        }

        // ---- MFMA: (32 x 512) h x (512 x 16) U-tile ----
        f32x4 acc0 = {0.f, 0.f, 0.f, 0.f};
        f32x4 acc1 = {0.f, 0.f, 0.f, 0.f};
        if (s > 0) {
            const unsigned short* hs = hstage[s & 1];
#pragma unroll
            for (int kc = 0; kc < 16; ++kc) {
                bf16x8 a0 = *(const bf16x8*)&hs[((size_t)(0 * 16 + kc) * 64 + l) * 8];
                bf16x8 a1 = *(const bf16x8*)&hs[((size_t)(1 * 16 + kc) * 64 + l) * 8];
                bf16x8 bw = *(const bf16x8*)&wlds[(((size_t)w * 16 + kc) * 64 + l) * 8];
                acc0 = __builtin_amdgcn_mfma_f32_16x16x32_bf16(a0, bw, acc0, 0, 0, 0);
                acc1 = __builtin_amdgcn_mfma_f32_16x16x32_bf16(a1, bw, acc1, 0, 0, 0);
            }
        }

        // ---- combine + EARLY per-mb publish; y stores ride the same drain ----
        unsigned int* hfw = h_frag + (size_t)((s + 1) & 1) * 8192;
#pragma unroll
        for (int mb = 0; mb < 2; ++mb) {
            f32x4 acc = mb ? acc1 : acc0;
            float hsel = 0.f;
#pragma unroll
            for (int r = 0; r < 4; ++r) {
                float v = acc[r] + bf2f(gcur[mb][r]);
                float x1 = __shfl_xor(v, 1, 64);
                float x2 = __shfl_xor(v, 2, 64);
                float x3 = __shfl_xor(v, 3, 64);  // independent (== shfl(shfl(v,1),2))
                bool b0 = (g & 1) != 0, b1 = (g & 2) != 0;
                float gf = b1 ? (b0 ? x3 : x2) : (b0 ? x1 : v);
                float gi = b1 ? (b0 ? x2 : x3) : (b0 ? v : x1);
                float go = b1 ? (b0 ? x1 : v) : (b0 ? x3 : x2);
                float gc = b1 ? (b0 ? v : x1) : (b0 ? x2 : x3);
                float ft = fsig(gf), it = fsig(gi), ot = fsig(go);
                float cn = it * ftanh(gc) + ft * cst[mb][r];
                cst[mb][r] = cn;
                float hn = ot * ftanh(cn);
                if (r == g) hsel = hn;
            }
            unsigned b16 = (unsigned)f2bf(hsel);
            unsigned ho = (unsigned)__shfl_xor((int)b16, 4, 64);
            unsigned hww = b16 | (ho << 16);
            float hof = __shfl_xor(hsel, 4, 64);
            if ((q & 1) == 0) {
                coh_st32(hfw + (mb ? fid1 : fid0), hww);  // h publish, earliest
                int row = (mb ? (T - 1 - s) : s) * 16 + m0;
                int col = mb * 512 + j0 + jl;
                if (LAYER == 0) {
                    *(unsigned int*)&y_bf[(size_t)row * 1024 + col] = hww;
                } else {
                    *(float2*)&y_f32[(size_t)row * 1024 + col] = make_float2(hsel, hof);
                }
            }
        }

        // ---- per-wave drain (h + y acks in parallel) -> per-wave flag ----
        vm_drain();
        if (l == 0) coh_st32(flagp, (unsigned)(s + 2));
    }
}

// ---------------- host ----------------

extern "C" void kernel_launch(void* const* d_in, const int* in_sizes, int n_in,
                              void* d_out, int out_size, void* d_ws, size_t ws_size,
                              hipStream_t stream) {
    (void)in_sizes; (void)n_in; (void)out_size; (void)ws_size;
    const int T = 1000, M = T * 16;
    const int K0 = 440, K0p = 448, K1 = 1024;

    char* ws = (char*)d_ws;
    size_t off = 0;
    auto alloc = [&](size_t bytes) -> void* {
        void* p = ws + off;
        off += (bytes + 255) & ~(size_t)255;
        return p;
    };
    unsigned short* G  = (unsigned short*)alloc((size_t)M * 2048 * 2);
    unsigned short* xp = (unsigned short*)alloc((size_t)M * K0p * 2);
    unsigned short* W0 = (unsigned short*)alloc((size_t)2048 * K0p * 2);
    unsigned short* W1 = (unsigned short*)alloc((size_t)2048 * K1 * 2);
    unsigned short* U0 = (unsigned short*)alloc((size_t)2048 * 512 * 2);
    unsigned short* U1 = (unsigned short*)alloc((size_t)2048 * 512 * 2);
    unsigned short* y0 = (unsigned short*)alloc((size_t)M * 1024 * 2);
    unsigned int* hf0  = (unsigned int*)alloc((size_t)2 * 8192 * 4);
    unsigned int* hf1  = (unsigned int*)alloc((size_t)2 * 8192 * 4);
    unsigned int* fl0  = (unsigned int*)alloc((size_t)128 * 32 * 4);
    unsigned int* fl1  = (unsigned int*)alloc((size_t)128 * 32 * 4);

    const float* x = (const float*)d_in[0];

    hipMemsetAsync(fl0, 0, 128 * 32 * 4, stream);
    hipMemsetAsync(fl1, 0, 128 * 32 * 4, stream);

    pack_x_kernel<<<2048, 256, 0, stream>>>(x, xp, M, K0, K0p);
    pack_w_kernel<<<1024, 256, 0, stream>>>((const float*)d_in[1], (const float*)d_in[4],
                                            (const float*)d_in[7], (const float*)d_in[10],
                                            W0, K0, K0p);
    pack_w_kernel<<<1024, 256, 0, stream>>>((const float*)d_in[3], (const float*)d_in[6],
                                            (const float*)d_in[9], (const float*)d_in[12],
                                            U0, 512, 512);
    pack_w_kernel<<<1024, 256, 0, stream>>>((const float*)d_in[13], (const float*)d_in[16],
                                            (const float*)d_in[19], (const float*)d_in[22],
                                            W1, K1, K1);
    pack_w_kernel<<<1024, 256, 0, stream>>>((const float*)d_in[15], (const float*)d_in[18],
                                            (const float*)d_in[21], (const float*)d_in[24],
                                            U1, 512, 512);

    dim3 blk(256);
    dim3 g0(M / 64, 2048 / 64);
    gemm_gates<<<g0, blk, 0, stream>>>(xp, W0, (const float*)d_in[2], (const float*)d_in[5],
                                       (const float*)d_in[8], (const float*)d_in[11], G, K0p);
    lstm_rec11<0><<<32, 256, 0, stream>>>(U0, G, y0, nullptr, hf0, fl0, T);
    gemm_gates<<<g0, blk, 0, stream>>>(y0, W1, (const float*)d_in[14], (const float*)d_in[17],
                                       (const float*)d_in[20], (const float*)d_in[23], G, K1);
    lstm_rec11<1><<<32, 256, 0, stream>>>(U1, G, nullptr, (float*)d_out, hf1, fl1, T);
}